// Round 3
// baseline (169.874 us; speedup 1.0000x reference)
//
#include <hip/hip_runtime.h>
#include <hip/hip_bf16.h>

#define EPS 1e-6f

typedef float  f32x4  __attribute__((ext_vector_type(4)));
typedef __bf16 bf16x8 __attribute__((ext_vector_type(8)));

// ---------- helpers ----------
static __device__ __forceinline__ unsigned short f2bf(float f) {
    unsigned int x = __float_as_uint(f);
    unsigned int r = (x + 0x7FFFu + ((x >> 16) & 1u)) >> 16;   // RNE
    return (unsigned short)r;
}

// ---------- kernel 1: row stats (fp32) + bf16 conversion, both matrices ----------
// grid = 1024 (protos) + 8192 (querys) = 9216 blocks, 256 threads
__global__ __launch_bounds__(256) void prep_kernel(
    const float* __restrict__ protos, const float* __restrict__ querys,
    unsigned short* __restrict__ pb, unsigned short* __restrict__ qb,
    float* __restrict__ p_sq, float* __restrict__ p_sum,
    float* __restrict__ q_sq, float* __restrict__ q_sum)
{
    const int b   = blockIdx.x;
    const int tid = threadIdx.x;
    const float* src; unsigned short* dst; float* rsq; float* rsum;
    if (b < 1024) {
        src = protos + (size_t)b * 1024; dst = pb + (size_t)b * 1024;
        rsq = p_sq + b; rsum = p_sum + b;
    } else {
        const int r = b - 1024;
        src = querys + (size_t)r * 1024; dst = qb + (size_t)r * 1024;
        rsq = q_sq + r; rsum = q_sum + r;
    }

    const float4 v = reinterpret_cast<const float4*>(src)[tid];
    float s  = v.x + v.y + v.z + v.w;
    float ss = v.x * v.x + v.y * v.y + v.z * v.z + v.w * v.w;

    ushort4 o;
    o.x = f2bf(v.x); o.y = f2bf(v.y); o.z = f2bf(v.z); o.w = f2bf(v.w);
    reinterpret_cast<ushort4*>(dst)[tid] = o;

    #pragma unroll
    for (int m = 32; m >= 1; m >>= 1) {
        s  += __shfl_xor(s, m, 64);
        ss += __shfl_xor(ss, m, 64);
    }
    __shared__ float red[8];
    const int wave = tid >> 6;
    if ((tid & 63) == 0) { red[wave] = s; red[4 + wave] = ss; }
    __syncthreads();
    if (tid == 0) {
        *rsum = red[0] + red[1] + red[2] + red[3];
        *rsq  = red[4] + red[5] + red[6] + red[7];
    }
}

// ---------- kernel 2: fused GEMM + softmax/entropy, row-panel per block ----------
// grid = 256 blocks x 512 threads (8 waves). Block owns rows br*32..+31, all 1024 cols.
// Wave w owns cols w*128..+127 (2 m-frags x 8 n-frags of 16x16x32 MFMA).
// No LDS staging: fragments loaded directly from global (P is L2-resident, Q is L1-reused).
__global__ __launch_bounds__(512, 2) void fused_kernel(
    const unsigned short* __restrict__ qb,   // [8192][1024] bf16 bits
    const unsigned short* __restrict__ pb,   // [1024][1024] bf16 bits
    const float* __restrict__ q_sq, const float* __restrict__ q_sum,
    const float* __restrict__ p_sq, const float* __restrict__ p_sum,
    float* __restrict__ post, float* __restrict__ c_out, float* __restrict__ h_out)
{
    __shared__ float se_l[8][32];
    __shared__ float te_l[8][32];
    __shared__ float mx_l[8][32];
    __shared__ float qs_l[32], qm_l[32], inv_l[32];

    const int tid  = threadIdx.x;
    const int w    = tid >> 6;
    const int lane = tid & 63;
    const int l15  = lane & 15;
    const int l4   = lane >> 4;
    const int row0 = blockIdx.x * 32;
    const int col0 = w * 128;

    if (tid < 32) { qs_l[tid] = q_sq[row0 + tid]; qm_l[tid] = q_sum[row0 + tid]; }
    __syncthreads();

    // per-thread column stats (col = col0 + n*16 + l15)
    float ps[8], pm[8];
    #pragma unroll
    for (int n = 0; n < 8; ++n) {
        const int c = col0 + n * 16 + l15;
        ps[n] = p_sq[c];
        pm[n] = p_sum[c];
    }

    // fragment base pointers
    const unsigned short* ap[2];
    const unsigned short* bp[8];
    #pragma unroll
    for (int m = 0; m < 2; ++m)
        ap[m] = qb + (size_t)(row0 + m * 16 + l15) * 1024 + l4 * 8;
    #pragma unroll
    for (int n = 0; n < 8; ++n)
        bp[n] = pb + (size_t)(col0 + n * 16 + l15) * 1024 + l4 * 8;

    f32x4 acc[2][8];
    #pragma unroll
    for (int m = 0; m < 2; ++m)
        #pragma unroll
        for (int n = 0; n < 8; ++n)
            acc[m][n] = (f32x4)0.0f;

    bf16x8 a0[2], b0[8], a1[2], b1[8];

#define LOADF(A, B, KK) do {                                                    \
    _Pragma("unroll")                                                           \
    for (int m = 0; m < 2; ++m) A[m] = *reinterpret_cast<const bf16x8*>(ap[m] + (KK)); \
    _Pragma("unroll")                                                           \
    for (int n = 0; n < 8; ++n) B[n] = *reinterpret_cast<const bf16x8*>(bp[n] + (KK)); \
} while (0)

#define MM(A, B) do {                                                           \
    _Pragma("unroll")                                                           \
    for (int m = 0; m < 2; ++m)                                                 \
        _Pragma("unroll")                                                       \
        for (int n = 0; n < 8; ++n)                                             \
            acc[m][n] = __builtin_amdgcn_mfma_f32_16x16x32_bf16(A[m], B[n], acc[m][n], 0, 0, 0); \
} while (0)

    LOADF(a0, b0, 0);
    #pragma unroll 1
    for (int kk = 0; kk < 960; kk += 64) {
        LOADF(a1, b1, kk + 32);
        MM(a0, b0);
        LOADF(a0, b0, kk + 64);
        MM(a1, b1);
    }
    LOADF(a1, b1, 992);
    MM(a0, b0);
    MM(a1, b1);

#undef LOADF
#undef MM

    // ---- epilogue: dist -> e = exp(-dist), in-register; per-row partials ----
    const float dee = 1024.0f * EPS * EPS;

    #pragma unroll
    for (int m = 0; m < 2; ++m) {
        #pragma unroll
        for (int r = 0; r < 4; ++r) {
            const int lr = m * 16 + l4 * 4 + r;
            const float qs = qs_l[lr], qm = qm_l[lr];
            float se = 0.0f, te = 0.0f, mx = 0.0f;
            #pragma unroll
            for (int n = 0; n < 8; ++n) {
                const float cross = acc[m][n][r];
                const float sq = qs + ps[n] - 2.0f * cross + 2.0f * EPS * (qm - pm[n]) + dee;
                const float dist = sqrtf(fmaxf(sq, 0.0f));
                const float e = __expf(-dist);
                acc[m][n][r] = e;
                se += e;
                te += e * dist;
                mx = fmaxf(mx, e);
            }
            #pragma unroll
            for (int msk = 8; msk >= 1; msk >>= 1) {
                se += __shfl_xor(se, msk, 64);
                te += __shfl_xor(te, msk, 64);
                mx = fmaxf(mx, __shfl_xor(mx, msk, 64));
            }
            if (l15 == 0) {
                se_l[w][lr] = se;
                te_l[w][lr] = te;
                mx_l[w][lr] = mx;
            }
        }
    }
    __syncthreads();

    if (tid < 32) {
        float s = 0.0f, t = 0.0f, mx = 0.0f;
        #pragma unroll
        for (int ww = 0; ww < 8; ++ww) {
            s += se_l[ww][tid];
            t += te_l[ww][tid];
            mx = fmaxf(mx, mx_l[ww][tid]);
        }
        const float inv = 1.0f / s;
        inv_l[tid] = inv;
        c_out[row0 + tid] = mx * inv;
        h_out[row0 + tid] = logf(s) + t * inv;   // h = t/s + log s
    }
    __syncthreads();

    // ---- normalized store ----
    #pragma unroll
    for (int m = 0; m < 2; ++m) {
        #pragma unroll
        for (int r = 0; r < 4; ++r) {
            const int lr = m * 16 + l4 * 4 + r;
            const float inv = inv_l[lr];
            #pragma unroll
            for (int n = 0; n < 8; ++n) {
                post[(size_t)(row0 + lr) * 1024 + col0 + n * 16 + l15] = acc[m][n][r] * inv;
            }
        }
    }
}

// ---------- launcher ----------
extern "C" void kernel_launch(void* const* d_in, const int* in_sizes, int n_in,
                              void* d_out, int out_size, void* d_ws, size_t ws_size,
                              hipStream_t stream) {
    const float* protos = (const float*)d_in[0];  // [1024,1024]
    const float* querys = (const float*)d_in[1];  // [8192,1024]

    float* out   = (float*)d_out;
    float* post  = out;                            // 8192*1024
    float* c_out = out + (size_t)8192 * 1024;      // 8192
    float* h_out = c_out + 8192;                   // 8192

    char* ws = (char*)d_ws;
    unsigned short* qb = (unsigned short*)ws;  ws += (size_t)8192 * 1024 * 2;
    unsigned short* pb = (unsigned short*)ws;  ws += (size_t)1024 * 1024 * 2;
    float* q_sq  = (float*)ws;  ws += 8192 * 4;
    float* q_sum = (float*)ws;  ws += 8192 * 4;
    float* p_sq  = (float*)ws;  ws += 1024 * 4;
    float* p_sum = (float*)ws;  ws += 1024 * 4;

    prep_kernel<<<9216, 256, 0, stream>>>(protos, querys, pb, qb, p_sq, p_sum, q_sq, q_sum);
    fused_kernel<<<256, 512, 0, stream>>>(qb, pb, q_sq, q_sum, p_sq, p_sum,
                                          post, c_out, h_out);
}

// Round 4
// 132.418 us; speedup vs baseline: 1.2829x; 1.2829x over previous
//
#include <hip/hip_runtime.h>
#include <hip/hip_bf16.h>

#define EPS 1e-6f

typedef float  f32x4  __attribute__((ext_vector_type(4)));
typedef __bf16 bf16x8 __attribute__((ext_vector_type(8)));

// ---------- helpers ----------
static __device__ __forceinline__ unsigned short f2bf(float f) {
    unsigned int x = __float_as_uint(f);
    unsigned int r = (x + 0x7FFFu + ((x >> 16) & 1u)) >> 16;   // RNE
    return (unsigned short)r;
}
static __device__ __forceinline__ float bf2f(unsigned short u) {
    return __uint_as_float((unsigned int)u << 16);
}

// ---------- kernel 1: row stats (fp32) + bf16 conversion, both matrices ----------
// grid = 1024 (protos) + 8192 (querys) = 9216 blocks, 256 threads
__global__ __launch_bounds__(256) void prep_kernel(
    const float* __restrict__ protos, const float* __restrict__ querys,
    unsigned short* __restrict__ pb, unsigned short* __restrict__ qb,
    float* __restrict__ p_sq, float* __restrict__ p_sum,
    float* __restrict__ q_sq, float* __restrict__ q_sum)
{
    const int b   = blockIdx.x;
    const int tid = threadIdx.x;
    const float* src; unsigned short* dst; float* rsq; float* rsum;
    if (b < 1024) {
        src = protos + (size_t)b * 1024; dst = pb + (size_t)b * 1024;
        rsq = p_sq + b; rsum = p_sum + b;
    } else {
        const int r = b - 1024;
        src = querys + (size_t)r * 1024; dst = qb + (size_t)r * 1024;
        rsq = q_sq + r; rsum = q_sum + r;
    }

    const float4 v = reinterpret_cast<const float4*>(src)[tid];
    float s  = v.x + v.y + v.z + v.w;
    float ss = v.x * v.x + v.y * v.y + v.z * v.z + v.w * v.w;

    ushort4 o;
    o.x = f2bf(v.x); o.y = f2bf(v.y); o.z = f2bf(v.z); o.w = f2bf(v.w);
    reinterpret_cast<ushort4*>(dst)[tid] = o;

    #pragma unroll
    for (int m = 32; m >= 1; m >>= 1) {
        s  += __shfl_xor(s, m, 64);
        ss += __shfl_xor(ss, m, 64);
    }
    __shared__ float red[8];
    const int wave = tid >> 6;
    if ((tid & 63) == 0) { red[wave] = s; red[4 + wave] = ss; }
    __syncthreads();
    if (tid == 0) {
        *rsum = red[0] + red[1] + red[2] + red[3];
        *rsq  = red[4] + red[5] + red[6] + red[7];
    }
}

// ---------- kernel 2: bf16 MFMA GEMM + dist/exp epilogue (proven R1 structure) ----------
// 128x128 tile, BK=32, 256 threads = 4 waves (2x2), each wave 64x64 (4x4 frags)
// e stored as bf16 (halves the intermediate write)
__global__ __launch_bounds__(256, 2) void gemm_exp_kernel(
    const unsigned short* __restrict__ qb,   // [8192][1024] bf16 bits
    const unsigned short* __restrict__ pb,   // [1024][1024] bf16 bits
    const float* __restrict__ q_sq, const float* __restrict__ q_sum,
    const float* __restrict__ p_sq, const float* __restrict__ p_sum,
    unsigned short* __restrict__ e_out,      // [8192][1024] bf16 un-normalized exp(-dist)
    float* __restrict__ row_s, float* __restrict__ row_t,
    unsigned int* __restrict__ row_m)
{
    __shared__ unsigned short As[128 * 32];
    __shared__ unsigned short Bs[128 * 32];

    const int tid  = threadIdx.x;
    const int lane = tid & 63;
    const int wave = tid >> 6;
    const int wr = wave >> 1, wc = wave & 1;
    const int l15 = lane & 15;
    const int l4  = lane >> 4;
    const int br = blockIdx.x, bc = blockIdx.y;

    f32x4 acc[4][4];
    #pragma unroll
    for (int m = 0; m < 4; ++m)
        #pragma unroll
        for (int n = 0; n < 4; ++n)
            acc[m][n] = (f32x4)0.0f;

    const size_t qbase = (size_t)(br * 128) * 1024;
    const size_t pbase = (size_t)(bc * 128) * 1024;
    const int c0 = tid, c1 = tid + 256;     // 16B chunks: row=c>>2, col8=(c&3)*8

    for (int kk = 0; kk < 1024; kk += 32) {
        __syncthreads();
        {
            const unsigned short* gq0 = qb + qbase + (size_t)(c0 >> 2) * 1024 + kk + (c0 & 3) * 8;
            const unsigned short* gq1 = qb + qbase + (size_t)(c1 >> 2) * 1024 + kk + (c1 & 3) * 8;
            const unsigned short* gp0 = pb + pbase + (size_t)(c0 >> 2) * 1024 + kk + (c0 & 3) * 8;
            const unsigned short* gp1 = pb + pbase + (size_t)(c1 >> 2) * 1024 + kk + (c1 & 3) * 8;
            __builtin_amdgcn_global_load_lds((const __attribute__((address_space(1))) void*)gq0,
                                             (__attribute__((address_space(3))) void*)(&As[c0 * 8]), 16, 0, 0);
            __builtin_amdgcn_global_load_lds((const __attribute__((address_space(1))) void*)gq1,
                                             (__attribute__((address_space(3))) void*)(&As[c1 * 8]), 16, 0, 0);
            __builtin_amdgcn_global_load_lds((const __attribute__((address_space(1))) void*)gp0,
                                             (__attribute__((address_space(3))) void*)(&Bs[c0 * 8]), 16, 0, 0);
            __builtin_amdgcn_global_load_lds((const __attribute__((address_space(1))) void*)gp1,
                                             (__attribute__((address_space(3))) void*)(&Bs[c1 * 8]), 16, 0, 0);
        }
        __syncthreads();

        bf16x8 a[4], b[4];
        #pragma unroll
        for (int m = 0; m < 4; ++m)
            a[m] = *reinterpret_cast<const bf16x8*>(&As[(wr * 64 + m * 16 + l15) * 32 + l4 * 8]);
        #pragma unroll
        for (int n = 0; n < 4; ++n)
            b[n] = *reinterpret_cast<const bf16x8*>(&Bs[(wc * 64 + n * 16 + l15) * 32 + l4 * 8]);
        #pragma unroll
        for (int m = 0; m < 4; ++m)
            #pragma unroll
            for (int n = 0; n < 4; ++n)
                acc[m][n] = __builtin_amdgcn_mfma_f32_16x16x32_bf16(a[m], b[n], acc[m][n], 0, 0, 0);
    }

    // ---- epilogue: dist -> e = exp(-dist); write e (bf16); per-row partials ----
    const int row0 = br * 128 + wr * 64;   // + m*16 + l4*4 + r
    const int col0 = bc * 128 + wc * 64;   // + n*16 + l15

    float ps[4], pm[4];
    #pragma unroll
    for (int n = 0; n < 4; ++n) {
        const int c = col0 + n * 16 + l15;
        ps[n] = p_sq[c];
        pm[n] = p_sum[c];
    }
    const float dee = 1024.0f * EPS * EPS;

    #pragma unroll
    for (int m = 0; m < 4; ++m) {
        #pragma unroll
        for (int r = 0; r < 4; ++r) {
            const int row = row0 + m * 16 + l4 * 4 + r;
            const float qs = q_sq[row], qm = q_sum[row];
            float se = 0.0f, te = 0.0f, mx = 0.0f;
            #pragma unroll
            for (int n = 0; n < 4; ++n) {
                const float cross = acc[m][n][r];
                const float sq = qs + ps[n] - 2.0f * cross + 2.0f * EPS * (qm - pm[n]) + dee;
                const float dist = sqrtf(fmaxf(sq, 0.0f));
                const float e = __expf(-dist);
                e_out[(size_t)row * 1024 + (col0 + n * 16 + l15)] = f2bf(e);
                se += e;
                te += e * dist;
                mx = fmaxf(mx, e);
            }
            #pragma unroll
            for (int msk = 8; msk >= 1; msk >>= 1) {
                se += __shfl_xor(se, msk, 64);
                te += __shfl_xor(te, msk, 64);
                mx = fmaxf(mx, __shfl_xor(mx, msk, 64));
            }
            if (l15 == 0) {
                atomicAdd(&row_s[row], se);
                atomicAdd(&row_t[row], te);
                atomicMax(&row_m[row], __float_as_uint(mx));
            }
        }
    }
}

// ---------- kernel 3: merged finalize + normalize ----------
// grid = 8192 blocks (one row each), 256 threads; reads bf16 e, writes f32 post
__global__ __launch_bounds__(256) void normfin_kernel(
    const unsigned short* __restrict__ e16,
    const float* __restrict__ row_s, const float* __restrict__ row_t,
    const unsigned int* __restrict__ row_m,
    float* __restrict__ post, float* __restrict__ c_out, float* __restrict__ h_out)
{
    const int row = blockIdx.x;
    const int tid = threadIdx.x;
    const float s   = row_s[row];
    const float inv = 1.0f / s;
    if (tid == 0) {
        c_out[row] = __uint_as_float(row_m[row]) * inv;
        h_out[row] = logf(s) + row_t[row] * inv;   // h = t/s + log s
    }
    const ushort4 ev = reinterpret_cast<const ushort4*>(e16 + (size_t)row * 1024)[tid];
    float4 o;
    o.x = bf2f(ev.x) * inv;
    o.y = bf2f(ev.y) * inv;
    o.z = bf2f(ev.z) * inv;
    o.w = bf2f(ev.w) * inv;
    reinterpret_cast<float4*>(post + (size_t)row * 1024)[tid] = o;
}

// ---------- launcher ----------
extern "C" void kernel_launch(void* const* d_in, const int* in_sizes, int n_in,
                              void* d_out, int out_size, void* d_ws, size_t ws_size,
                              hipStream_t stream) {
    const float* protos = (const float*)d_in[0];  // [1024,1024]
    const float* querys = (const float*)d_in[1];  // [8192,1024]

    float* out   = (float*)d_out;
    float* post  = out;                            // 8192*1024
    float* c_out = out + (size_t)8192 * 1024;      // 8192
    float* h_out = c_out + 8192;                   // 8192

    char* ws = (char*)d_ws;
    unsigned short* qb  = (unsigned short*)ws;  ws += (size_t)8192 * 1024 * 2;
    unsigned short* pb  = (unsigned short*)ws;  ws += (size_t)1024 * 1024 * 2;
    unsigned short* e16 = (unsigned short*)ws;  ws += (size_t)8192 * 1024 * 2;
    float* q_sq  = (float*)ws;  ws += 8192 * 4;
    float* q_sum = (float*)ws;  ws += 8192 * 4;
    float* p_sq  = (float*)ws;  ws += 1024 * 4;
    float* p_sum = (float*)ws;  ws += 1024 * 4;
    float* row_s = (float*)ws;  ws += 8192 * 4;
    float* row_t = (float*)ws;  ws += 8192 * 4;
    unsigned int* row_m = (unsigned int*)ws;  ws += 8192 * 4;

    // zero the atomic accumulators (row_s, row_t, row_m are contiguous)
    (void)hipMemsetAsync(row_s, 0, 3 * 8192 * sizeof(float), stream);

    prep_kernel<<<9216, 256, 0, stream>>>(protos, querys, pb, qb, p_sq, p_sum, q_sq, q_sum);
    gemm_exp_kernel<<<dim3(64, 8), 256, 0, stream>>>(qb, pb, q_sq, q_sum, p_sq, p_sum,
                                                     e16, row_s, row_t, row_m);
    normfin_kernel<<<8192, 256, 0, stream>>>(e16, row_s, row_t, row_m, post, c_out, h_out);
}